// Round 1
// baseline (982.397 us; speedup 1.0000x reference)
//
#include <hip/hip_runtime.h>
#include <math.h>

#define DIM    768
#define PE     200
#define LSPAN  20
#define NPAIRS 256
#define ROWS   5120
#define EMB    128
#define VOCAB  30522

typedef __attribute__((ext_vector_type(8))) short short8;
typedef __attribute__((ext_vector_type(4))) float floatx4;

__device__ inline unsigned short f2bf(float f) {
    union { float f; unsigned int u; } v; v.f = f;
    unsigned int r = v.u + 0x7fffu + ((v.u >> 16) & 1u);
    return (unsigned short)(r >> 16);
}
__device__ inline float gelu_exact(float x) {
    return 0.5f * x * (1.0f + erff(x * 0.70710678118654752f));
}

// ---------- weight prep ----------
__global__ void k_f32_to_bf16_vec4(const float* __restrict__ src, unsigned short* __restrict__ dst, int n4) {
    int i = blockIdx.x * blockDim.x + threadIdx.x;
    if (i >= n4) return;
    float4 v = ((const float4*)src)[i];
    ushort4 o;
    o.x = f2bf(v.x); o.y = f2bf(v.y); o.z = f2bf(v.z); o.w = f2bf(v.w);
    ((ushort4*)dst)[i] = o;
}

// dst[c*R + r] = bf16(src[r*C + c])   (src is [R][C], dst is [C][R])
__global__ void k_transpose_bf16(const float* __restrict__ src, unsigned short* __restrict__ dst, int R, int C) {
    int i = blockIdx.x * blockDim.x + threadIdx.x;
    if (i >= R * C) return;
    int r = i / C, c = i % C;
    dst[c * R + r] = f2bf(src[i]);
}

// ---------- posW[l][j] = sum_k pos_emb[l][k] * W1[1536+k][j] + b1[j] ----------
__global__ __launch_bounds__(256) void k_posW(const float* __restrict__ pos_emb, const float* __restrict__ W1,
                                              const float* __restrict__ b1, float* __restrict__ posW) {
    __shared__ float pe_s[PE];
    int l = blockIdx.x, tid = threadIdx.x;
    if (tid < PE) pe_s[tid] = pos_emb[l * PE + tid];
    __syncthreads();
    for (int jj = 0; jj < 3; ++jj) {
        int j = jj * 256 + tid;
        float acc = b1[j];
        for (int k = 0; k < PE; ++k)
            acc += pe_s[k] * W1[(size_t)(2 * DIM + k) * DIM + j];
        posW[l * DIM + j] = acc;
    }
}

// ---------- pairW[p][j] = lh[p]@W1a + rh[p]@W1b ----------
__global__ __launch_bounds__(256) void k_pairW(const float* __restrict__ hs, const int* __restrict__ pairs,
                                               const float* __restrict__ W1, float* __restrict__ pairW) {
    __shared__ float lh_s[4][DIM];
    __shared__ float rh_s[4][DIM];
    int tid = threadIdx.x;
    int jc = blockIdx.x;   // 0..2
    int g  = blockIdx.y;   // 0..63
    for (int p4 = 0; p4 < 4; ++p4) {
        int p = g * 4 + p4;
        int batch = p >> 5;
        int li = pairs[p * 2 + 0];
        int ri = pairs[p * 2 + 1];
        const float* lrow = hs + ((size_t)batch * 512 + li) * DIM;
        const float* rrow = hs + ((size_t)batch * 512 + ri) * DIM;
        for (int jj = 0; jj < 3; ++jj) {
            lh_s[p4][jj * 256 + tid] = lrow[jj * 256 + tid];
            rh_s[p4][jj * 256 + tid] = rrow[jj * 256 + tid];
        }
    }
    __syncthreads();
    int j = jc * 256 + tid;
    float a0 = 0.f, a1 = 0.f, a2 = 0.f, a3 = 0.f;
    for (int k = 0; k < DIM; ++k) {
        float w1a = W1[(size_t)k * DIM + j];
        float w1b = W1[(size_t)(DIM + k) * DIM + j];
        a0 += lh_s[0][k] * w1a + rh_s[0][k] * w1b;
        a1 += lh_s[1][k] * w1a + rh_s[1][k] * w1b;
        a2 += lh_s[2][k] * w1a + rh_s[2][k] * w1b;
        a3 += lh_s[3][k] * w1a + rh_s[3][k] * w1b;
    }
    pairW[(size_t)(g * 4 + 0) * DIM + j] = a0;
    pairW[(size_t)(g * 4 + 1) * DIM + j] = a1;
    pairW[(size_t)(g * 4 + 2) * DIM + j] = a2;
    pairW[(size_t)(g * 4 + 3) * DIM + j] = a3;
}

// ---------- h1[row] = LN(gelu(pairW[p] + posW[l])) -> bf16 ----------
__global__ __launch_bounds__(256) void k_h1(const float* __restrict__ pairW, const float* __restrict__ posW,
                                            const float* __restrict__ g1, const float* __restrict__ be1,
                                            unsigned short* __restrict__ h1) {
    __shared__ float xs[DIM];
    __shared__ float red[10];
    int row = blockIdx.x, tid = threadIdx.x;
    int p = row / LSPAN, l = row % LSPAN;
    float s = 0.f, s2 = 0.f;
    for (int jj = 0; jj < 3; ++jj) {
        int j = jj * 256 + tid;
        float v = pairW[(size_t)p * DIM + j] + posW[l * DIM + j];
        float gv = gelu_exact(v);
        xs[j] = gv;
        s += gv; s2 += gv * gv;
    }
    for (int off = 32; off > 0; off >>= 1) { s += __shfl_down(s, off); s2 += __shfl_down(s2, off); }
    int w = tid >> 6, lane = tid & 63;
    if (lane == 0) { red[w] = s; red[4 + w] = s2; }
    __syncthreads();
    if (tid == 0) {
        float a = red[0] + red[1] + red[2] + red[3];
        float b = red[4] + red[5] + red[6] + red[7];
        float mu = a / DIM;
        float var = fmaxf(b / DIM - mu * mu, 0.f);
        red[8] = mu; red[9] = rsqrtf(var + 1e-12f);
    }
    __syncthreads();
    float mu = red[8], rstd = red[9];
    for (int jj = 0; jj < 3; ++jj) {
        int j = jj * 256 + tid;
        h1[(size_t)row * DIM + j] = f2bf((xs[j] - mu) * rstd * g1[j] + be1[j]);
    }
}

// ---------- row LN over 768: fp32 in -> bf16 out ----------
__global__ __launch_bounds__(256) void k_ln(const float* __restrict__ in, const float* __restrict__ gamma,
                                            const float* __restrict__ beta, unsigned short* __restrict__ out) {
    __shared__ float xs[DIM];
    __shared__ float red[10];
    int row = blockIdx.x, tid = threadIdx.x;
    float s = 0.f, s2 = 0.f;
    for (int jj = 0; jj < 3; ++jj) {
        int j = jj * 256 + tid;
        float v = in[(size_t)row * DIM + j];
        xs[j] = v;
        s += v; s2 += v * v;
    }
    for (int off = 32; off > 0; off >>= 1) { s += __shfl_down(s, off); s2 += __shfl_down(s2, off); }
    int w = tid >> 6, lane = tid & 63;
    if (lane == 0) { red[w] = s; red[4 + w] = s2; }
    __syncthreads();
    if (tid == 0) {
        float a = red[0] + red[1] + red[2] + red[3];
        float b = red[4] + red[5] + red[6] + red[7];
        float mu = a / DIM;
        float var = fmaxf(b / DIM - mu * mu, 0.f);
        red[8] = mu; red[9] = rsqrtf(var + 1e-12f);
    }
    __syncthreads();
    float mu = red[8], rstd = red[9];
    for (int jj = 0; jj < 3; ++jj) {
        int j = jj * 256 + tid;
        out[(size_t)row * DIM + j] = f2bf((xs[j] - mu) * rstd * gamma[j] + beta[j]);
    }
}

// ---------- BT-GEMM: C[M,N] = A[M,K] * B[N,K]^T  (bf16 in, fp32 acc) ----------
// EPI 0: store fp32. EPI 1: v=gelu(v+bias[col]) store fp32. EPI 2: v+=bias[col] store bf16.
template <int EPI>
__global__ __launch_bounds__(256) void gemm_bt(const unsigned short* __restrict__ A,
                                               const unsigned short* __restrict__ B,
                                               const float* __restrict__ bias, void* __restrict__ Cout,
                                               int M, int N, int K, int ldc) {
    const int LDT = 136;  // LDS row stride (bf16 elems), +16B pad: conflict-free frag reads
    __shared__ unsigned short As[64 * LDT];
    __shared__ unsigned short Bs[64 * LDT];
    int tid = threadIdx.x;
    int m0 = blockIdx.x * 64;
    int n0 = blockIdx.y * 64;
    int w = tid >> 6, lane = tid & 63;
    int quad = lane >> 4, r16 = lane & 15;
    int wm = (w >> 1) * 32, wn = (w & 1) * 32;

    floatx4 acc[2][2] = {};

    for (int k0 = 0; k0 < K; k0 += 128) {
#pragma unroll
        for (int i = 0; i < 4; ++i) {
            int c = tid + i * 256;      // 0..1023
            int row = c >> 4;
            int kc = (c & 15) * 8;
            uint4 v = *(const uint4*)(&A[(size_t)(m0 + row) * K + k0 + kc]);
            *(uint4*)(&As[row * LDT + kc]) = v;
        }
#pragma unroll
        for (int i = 0; i < 4; ++i) {
            int c = tid + i * 256;
            int row = c >> 4;
            int kc = (c & 15) * 8;
            uint4 v = make_uint4(0u, 0u, 0u, 0u);
            if (n0 + row < N)
                v = *(const uint4*)(&B[(size_t)(n0 + row) * K + k0 + kc]);
            *(uint4*)(&Bs[row * LDT + kc]) = v;
        }
        __syncthreads();
#pragma unroll
        for (int kk = 0; kk < 4; ++kk) {
            short8 a0 = *(const short8*)(&As[(wm + 0 * 16 + r16) * LDT + kk * 32 + quad * 8]);
            short8 a1 = *(const short8*)(&As[(wm + 1 * 16 + r16) * LDT + kk * 32 + quad * 8]);
            short8 b0 = *(const short8*)(&Bs[(wn + 0 * 16 + r16) * LDT + kk * 32 + quad * 8]);
            short8 b1 = *(const short8*)(&Bs[(wn + 1 * 16 + r16) * LDT + kk * 32 + quad * 8]);
            acc[0][0] = __builtin_amdgcn_mfma_f32_16x16x32_bf16(a0, b0, acc[0][0], 0, 0, 0);
            acc[0][1] = __builtin_amdgcn_mfma_f32_16x16x32_bf16(a0, b1, acc[0][1], 0, 0, 0);
            acc[1][0] = __builtin_amdgcn_mfma_f32_16x16x32_bf16(a1, b0, acc[1][0], 0, 0, 0);
            acc[1][1] = __builtin_amdgcn_mfma_f32_16x16x32_bf16(a1, b1, acc[1][1], 0, 0, 0);
        }
        __syncthreads();
    }

#pragma unroll
    for (int mt = 0; mt < 2; ++mt)
#pragma unroll
        for (int nt = 0; nt < 2; ++nt)
#pragma unroll
            for (int r = 0; r < 4; ++r) {
                int row = m0 + wm + mt * 16 + quad * 4 + r;
                int col = n0 + wn + nt * 16 + r16;
                if (col < N) {
                    float v = acc[mt][nt][r];
                    if (EPI == 1) {
                        v = gelu_exact(v + bias[col]);
                        ((float*)Cout)[(size_t)row * ldc + col] = v;
                    } else if (EPI == 2) {
                        v += bias[col];
                        ((unsigned short*)Cout)[(size_t)row * ldc + col] = f2bf(v);
                    } else {
                        ((float*)Cout)[(size_t)row * ldc + col] = v;
                    }
                }
            }
}

extern "C" void kernel_launch(void* const* d_in, const int* in_sizes, int n_in,
                              void* d_out, int out_size, void* d_ws, size_t ws_size,
                              hipStream_t stream) {
    const float* hs      = (const float*)d_in[0];
    const int*   pairs   = (const int*)d_in[1];
    const float* pos_emb = (const float*)d_in[2];
    const float* W1      = (const float*)d_in[3];
    const float* b1      = (const float*)d_in[4];
    const float* g1      = (const float*)d_in[5];
    const float* be1     = (const float*)d_in[6];
    const float* W2      = (const float*)d_in[7];
    const float* b2      = (const float*)d_in[8];
    const float* g2      = (const float*)d_in[9];
    const float* be2     = (const float*)d_in[10];
    const float* Wp      = (const float*)d_in[11];
    const float* bp      = (const float*)d_in[12];
    const float* Wdec    = (const float*)d_in[13];
    float* out = (float*)d_out;

    char* ws = (char*)d_ws;
    float*          posW  = (float*)(ws + 0);                 //  20*768*4   = 61440
    float*          pairW = (float*)(ws + 61440);             // 256*768*4   = 786432
    unsigned short* h1    = (unsigned short*)(ws + 847872);   // 5120*768*2  = 7864320
    unsigned short* W2T   = (unsigned short*)(ws + 8712192);  // 768*768*2   = 1179648
    float*          y     = (float*)(ws + 9891840);           // 5120*768*4  = 15728640
    unsigned short* h2    = (unsigned short*)(ws + 25620480); // 5120*768*2  = 7864320
    unsigned short* WpT   = (unsigned short*)(ws + 33484800); // 128*768*2   = 196608
    unsigned short* h3    = (unsigned short*)(ws + 33681408); // 5120*128*2  = 1310720
    unsigned short* WdecB = (unsigned short*)(ws + 34992128); // 30522*128*2 = 7813632
    // total ws usage: 42805760 bytes

    // weight prep
    int n4 = (VOCAB * EMB) / 4;  // 976704
    k_f32_to_bf16_vec4<<<(n4 + 255) / 256, 256, 0, stream>>>(Wdec, WdecB, n4);
    k_transpose_bf16<<<(DIM * DIM + 255) / 256, 256, 0, stream>>>(W2, W2T, DIM, DIM);
    k_transpose_bf16<<<(DIM * EMB + 255) / 256, 256, 0, stream>>>(Wp, WpT, DIM, EMB);

    // layer-1 structural decomposition
    k_posW<<<LSPAN, 256, 0, stream>>>(pos_emb, W1, b1, posW);
    k_pairW<<<dim3(3, 64), 256, 0, stream>>>(hs, pairs, W1, pairW);
    k_h1<<<ROWS, 256, 0, stream>>>(pairW, posW, g1, be1, h1);

    // layer 2: y = gelu(h1@W2 + b2); h2 = LN(y)
    gemm_bt<1><<<dim3(ROWS / 64, DIM / 64), 256, 0, stream>>>(h1, W2T, b2, y, ROWS, DIM, DIM, DIM);
    k_ln<<<ROWS, 256, 0, stream>>>(y, g2, be2, h2);

    // projection: h3 = h2@Wp + bp
    gemm_bt<2><<<dim3(ROWS / 64, EMB / 64), 256, 0, stream>>>(h2, WpT, bp, h3, ROWS, EMB, DIM, EMB);

    // decoder: out = h3 @ Wdec^T
    gemm_bt<0><<<dim3(ROWS / 64, (VOCAB + 63) / 64), 256, 0, stream>>>(h3, WdecB, nullptr, out, ROWS, VOCAB, EMB, VOCAB);
}